// Round 1
// baseline (288.323 us; speedup 1.0000x reference)
//
#include <hip/hip_runtime.h>
#include <stdint.h>

typedef unsigned short u16;
typedef __attribute__((ext_vector_type(8))) short short8;
typedef __attribute__((ext_vector_type(4))) float f32x4;

#define NBATCH 32
#define ICH 256
#define OCH 256
#define HH 56
#define WW 56
#define HP 58
#define WP 58
#define PIX (HH*WW)          // 3136
#define CHUNKS 49            // 3136/64
#define BM 64
#define BK 32
#define BKP 40               // +8 bf16 pad: row stride 80B, breaks bank conflicts
#define MTILES (NBATCH*CHUNKS)   // 1568

// workspace layout (bytes)
#define XBP_BYTES ((size_t)NBATCH*HP*WP*ICH*2)       // 55,115,776 per tensor
#define OFF_XBP1  ((size_t)0)
#define OFF_XBP2  (XBP_BYTES)
#define OFF_WBT   (2*XBP_BYTES)
#define WBT_BYTES ((size_t)9*OCH*ICH*2)              // 1,179,648
#define OFF_FLAG  (OFF_WBT + WBT_BYTES)
#define WS_NEED   (OFF_FLAG + 64)

__global__ void k_zero(uint4* p, int n16) {
    int i = blockIdx.x * blockDim.x + threadIdx.x;
    int stride = gridDim.x * blockDim.x;
    uint4 z = {0u, 0u, 0u, 0u};
    for (; i < n16; i += stride) p[i] = z;
}

// wbT[kk][oc][c] = sign(weight[oc][c][ky][kx]) as bf16 bits
__global__ void k_repack_w(const float* __restrict__ w, u16* __restrict__ wbT) {
    int idx = blockIdx.x * 256 + threadIdx.x;
    int c  = idx & 255;
    int oc = (idx >> 8) & 255;
    int kk = idx >> 16;
    float v = w[(oc * ICH + c) * 9 + kk];
    wbT[idx] = (v > 0.f) ? (u16)0x3F80 : ((v < 0.f) ? (u16)0xBF80 : (u16)0);
}

__global__ void k_flag(const float* __restrict__ s1, const float* __restrict__ s2,
                       int* __restrict__ flag) {
    __shared__ int bad;
    int t = threadIdx.x;
    if (t == 0) bad = 0;
    __syncthreads();
    if (s1[t] != s2[t]) atomicAdd(&bad, 1);
    __syncthreads();
    if (t == 0) *flag = (bad == 0) ? 1 : 0;
}

// NCHW fp32 -> two halo-padded NHWC bf16 tensors: xbp[n][y+1][x+1][c] = sign(x + shift)
__global__ __launch_bounds__(256) void k_repack_x(
    const float* __restrict__ x, const float* __restrict__ sh1,
    const float* __restrict__ sh2, u16* __restrict__ xbp1, u16* __restrict__ xbp2) {
    __shared__ float lds[64 * 68];
    int t = threadIdx.x;
    int b = blockIdx.x;
    int n = b / CHUNKS;
    int p0 = (b % CHUNKS) * 64;

    // write-phase mapping: 4 threads per pixel, 16 channels each
    int pixw = t >> 2;              // 0..63
    int c16  = (t & 3) * 16;
    int pw = p0 + pixw;
    int yw = pw / WW, xw = pw % WW;
    size_t obase = ((size_t)(n * HP + yw + 1) * WP + (xw + 1)) * ICH;

    // load-phase mapping
    int cl = t >> 4;                // 0..15
    int p4 = (t & 15) * 4;

    for (int cc = 0; cc < ICH; cc += 64) {
        __syncthreads();
#pragma unroll
        for (int i = 0; i < 4; ++i) {
            float4 v = *(const float4*)(x + (size_t)(n * ICH + cc + cl + i * 16) * PIX + p0 + p4);
            *(float4*)(&lds[(cl + i * 16) * 68 + p4]) = v;
        }
        __syncthreads();
        short8 r1lo, r1hi, r2lo, r2hi;
#pragma unroll
        for (int k = 0; k < 16; ++k) {
            int c = c16 + k;
            float v = lds[c * 68 + pixw];
            float a1 = v + sh1[cc + c];
            float a2 = v + sh2[cc + c];
            short s1 = (a1 > 0.f) ? (short)0x3F80 : ((a1 < 0.f) ? (short)(u16)0xBF80 : (short)0);
            short s2 = (a2 > 0.f) ? (short)0x3F80 : ((a2 < 0.f) ? (short)(u16)0xBF80 : (short)0);
            if (k < 8) { r1lo[k] = s1; r2lo[k] = s2; }
            else       { r1hi[k - 8] = s1; r2hi[k - 8] = s2; }
        }
        *(short8*)(xbp1 + obase + cc + c16)     = r1lo;
        *(short8*)(xbp1 + obase + cc + c16 + 8) = r1hi;
        *(short8*)(xbp2 + obase + cc + c16)     = r2lo;
        *(short8*)(xbp2 + obase + cc + c16 + 8) = r2hi;
    }
}

// Implicit-GEMM binary conv. Block: 256 threads = 4 waves. Tile: BM=64 pixels x 256 oc.
// Wave w owns oc [w*64, w*64+64). K = 9 taps x 256 channels, BK=32 per step.
template <bool EQ>
__global__ __launch_bounds__(256) void k_bgemm(
    const u16* __restrict__ xbp1, const u16* __restrict__ xbp2,
    const u16* __restrict__ wbT, const float* __restrict__ bias,
    const float* __restrict__ w1, const int* __restrict__ flag,
    float* __restrict__ out) {
    if ((*flag != 0) != EQ) return;   // block-uniform; exactly one instantiation runs

    __shared__ u16 As1[BM * BKP];       // 5.0 KB
    __shared__ u16 Bs[OCH * BKP];       // 20.0 KB
    constexpr int A2N = EQ ? 8 : BM * BKP;
    __shared__ u16 As2[A2N];

    int t = threadIdx.x;
    int b = blockIdx.x;
    int n = b / CHUNKS;
    int p0 = (b % CHUNKS) * 64;

    // staging mapping: 4 threads per row, 8 bf16 (16B) each
    int spix = t >> 2;              // 0..63
    int c8   = (t & 3) * 8;
    int sp = p0 + spix;
    int sy = sp / WW, sx = sp % WW;
    size_t abase = ((size_t)(n * HP + sy + 1) * WP + (sx + 1)) * ICH + c8;

    int l = t & 63, w = t >> 6;
    int lr = l & 15, lq = l >> 4;

    f32x4 acc[4][4];
    f32x4 acc2[4][4];
#pragma unroll
    for (int i = 0; i < 4; ++i)
#pragma unroll
        for (int j = 0; j < 4; ++j) {
            acc[i][j] = (f32x4){0.f, 0.f, 0.f, 0.f};
            acc2[i][j] = (f32x4){0.f, 0.f, 0.f, 0.f};
        }

    for (int kk = 0; kk < 9; ++kk) {
        int kdisp = ((kk / 3 - 1) * WP + (kk % 3 - 1)) * ICH;
        const u16* ap1 = xbp1 + abase + kdisp;
        const u16* ap2 = xbp2 + abase + kdisp;
        const u16* bp  = wbT + (size_t)kk * OCH * ICH + spix * ICH + c8;
        for (int cc = 0; cc < ICH; cc += BK) {
            short8 ar1 = *(const short8*)(ap1 + cc);
            short8 ar2;
            if constexpr (!EQ) ar2 = *(const short8*)(ap2 + cc);
            short8 br0 = *(const short8*)(bp + cc);
            short8 br1 = *(const short8*)(bp + 64 * ICH + cc);
            short8 br2 = *(const short8*)(bp + 128 * ICH + cc);
            short8 br3 = *(const short8*)(bp + 192 * ICH + cc);
            __syncthreads();
            *(short8*)(&As1[spix * BKP + c8]) = ar1;
            if constexpr (!EQ) *(short8*)(&As2[spix * BKP + c8]) = ar2;
            *(short8*)(&Bs[(spix)*BKP + c8])       = br0;
            *(short8*)(&Bs[(spix + 64) * BKP + c8])  = br1;
            *(short8*)(&Bs[(spix + 128) * BKP + c8]) = br2;
            *(short8*)(&Bs[(spix + 192) * BKP + c8]) = br3;
            __syncthreads();
            short8 af[4], bf[4];
#pragma unroll
            for (int i = 0; i < 4; ++i)
                af[i] = *(const short8*)(&As1[(i * 16 + lr) * BKP + lq * 8]);
#pragma unroll
            for (int i = 0; i < 4; ++i)
                bf[i] = *(const short8*)(&Bs[(w * 64 + i * 16 + lr) * BKP + lq * 8]);
#pragma unroll
            for (int mi = 0; mi < 4; ++mi)
#pragma unroll
                for (int ni = 0; ni < 4; ++ni)
                    acc[mi][ni] = __builtin_amdgcn_mfma_f32_16x16x32_bf16(
                        af[mi], bf[ni], acc[mi][ni], 0, 0, 0);
            if constexpr (!EQ) {
                short8 af2[4];
#pragma unroll
                for (int i = 0; i < 4; ++i)
                    af2[i] = *(const short8*)(&As2[(i * 16 + lr) * BKP + lq * 8]);
#pragma unroll
                for (int mi = 0; mi < 4; ++mi)
#pragma unroll
                    for (int ni = 0; ni < 4; ++ni)
                        acc2[mi][ni] = __builtin_amdgcn_mfma_f32_16x16x32_bf16(
                            af2[mi], bf[ni], acc2[mi][ni], 0, 0, 0);
            }
        }
    }

    float w1v = w1[0];
#pragma unroll
    for (int ni = 0; ni < 4; ++ni) {
        int oc = w * 64 + ni * 16 + lr;
        float bv = bias[oc];
#pragma unroll
        for (int mi = 0; mi < 4; ++mi) {
            int pixel = p0 + mi * 16 + lq * 4;
            f32x4 r;
            if constexpr (EQ) {
                float s = 1.f + w1v;
#pragma unroll
                for (int j = 0; j < 4; ++j) r[j] = (acc[mi][ni][j] + bv) * s;
            } else {
                float bb = (1.f + w1v) * bv;
#pragma unroll
                for (int j = 0; j < 4; ++j)
                    r[j] = acc[mi][ni][j] + w1v * acc2[mi][ni][j] + bb;
            }
            *(f32x4*)(out + (size_t)(n * OCH + oc) * PIX + pixel) = r;
        }
    }
}

extern "C" void kernel_launch(void* const* d_in, const int* in_sizes, int n_in,
                              void* d_out, int out_size, void* d_ws, size_t ws_size,
                              hipStream_t stream) {
    const float* x    = (const float*)d_in[0];
    const float* sh1  = (const float*)d_in[1];
    const float* sh2  = (const float*)d_in[2];
    const float* wgt  = (const float*)d_in[3];
    const float* bias = (const float*)d_in[4];
    const float* w1   = (const float*)d_in[5];
    float* out = (float*)d_out;
    char* ws = (char*)d_ws;
    if (ws_size < WS_NEED) return;   // would corrupt otherwise; visible as validation fail

    u16* xbp1 = (u16*)(ws + OFF_XBP1);
    u16* xbp2 = (u16*)(ws + OFF_XBP2);
    u16* wbT  = (u16*)(ws + OFF_WBT);
    int* flag = (int*)(ws + OFF_FLAG);

    k_zero<<<2048, 256, 0, stream>>>((uint4*)ws, (int)(2 * XBP_BYTES / 16));
    k_repack_w<<<(9 * OCH * ICH) / 256, 256, 0, stream>>>(wgt, wbT);
    k_flag<<<1, 256, 0, stream>>>(sh1, sh2, flag);
    k_repack_x<<<MTILES, 256, 0, stream>>>(x, sh1, sh2, xbp1, xbp2);
    k_bgemm<true><<<MTILES, 256, 0, stream>>>(xbp1, xbp2, wbT, bias, w1, flag, out);
    k_bgemm<false><<<MTILES, 256, 0, stream>>>(xbp1, xbp2, wbT, bias, w1, flag, out);
}